// Round 4
// baseline (1182.651 us; speedup 1.0000x reference)
//
#include <hip/hip_runtime.h>
#include <hip/hip_bf16.h>

// ---------------- problem constants ----------------
#define NTOK   65536          // B*H*W = 4*128*128
#define E_     512
#define NH_    16
#define HD_    32
#define DFF_   2048
#define N3E    1536           // 3*E

typedef __attribute__((ext_vector_type(8))) short short8;
typedef __attribute__((ext_vector_type(4))) short short4t;
typedef __attribute__((ext_vector_type(4))) float floatx4;

__device__ inline float b2f(short u) {
    union { float f; unsigned int i; } x;
    x.i = ((unsigned int)(unsigned short)u) << 16;
    return x.f;
}
__device__ inline short f2bs(float f) {
    __hip_bfloat16 h = __float2bfloat16(f);
    return *reinterpret_cast<short*>(&h);
}

// ---------------- fp32 -> bf16 convert ----------------
__global__ __launch_bounds__(256) void cvt_kernel(const float* __restrict__ in,
                                                  __hip_bfloat16* __restrict__ out, int n) {
    int i = (blockIdx.x * 256 + threadIdx.x) * 8;
    if (i >= n) return;
    if (i + 7 < n) {
        float4 a = *(const float4*)(in + i);
        float4 b = *(const float4*)(in + i + 4);
        short8 o;
        o[0] = f2bs(a.x); o[1] = f2bs(a.y); o[2] = f2bs(a.z); o[3] = f2bs(a.w);
        o[4] = f2bs(b.x); o[5] = f2bs(b.y); o[6] = f2bs(b.z); o[7] = f2bs(b.w);
        *(short8*)(out + i) = o;
    } else {
        for (int u = i; u < n; ++u) out[u] = __float2bfloat16(in[u]);
    }
}

// ---------------- pipelined MFMA GEMM: C = A @ Bw^T + bias (+epilogue) --------
// BM=128, BN=256, BK=64, 512 threads = 8 waves (2M x 4N), 64x64 C per wave.
// Double-buffered LDS (96 KB), depth-1 prefetch with counted vmcnt(6).
// LDS slot-XOR swizzle applied as pre-swizzled GLOBAL source + swizzled read.
// EPI 0: store bf16(out)                      (qkv proj)
// EPI 1: + res(float) -> store float          (out proj + x residual)
// EPI 2: relu -> store bf16                   (lin1)
// EPI 3: + res(bf16)  -> store float          (lin2 + z residual)
template<int EPI>
__global__ __launch_bounds__(512) void gemm2_kernel(
    const __hip_bfloat16* __restrict__ A,
    const __hip_bfloat16* __restrict__ Bw,
    const float* __restrict__ bias,
    const void* __restrict__ res,
    void* __restrict__ out,
    int M, int N, int K)
{
    __shared__ __align__(16) short As[2][128 * 64];   // 32 KB
    __shared__ __align__(16) short Bs[2][256 * 64];   // 64 KB

    const int tid  = threadIdx.x;
    const int wid  = tid >> 6;
    const int lane = tid & 63;
    const int tileN = blockIdx.x * 256;
    const int tileM = blockIdx.y * 128;

    const int wm = (wid >> 2) * 64;     // wave M offset (2 rows of waves)
    const int wn = (wid & 3) * 64;      // wave N offset (4 cols of waves)
    const int lm = lane & 15;
    const int g  = lane >> 4;

    // staging geometry: lane l -> dest row group + (l>>3), dest 16B-slot (l&7).
    // Source col-slot = destslot ^ (row&7)  (involution, matches read-side XOR).
    const int lr = lane >> 3;
    const int ss = (lane & 7) ^ lr;     // pre-swizzled source slot

    const __hip_bfloat16* gA = A  + (size_t)(tileM + wid * 16 + lr) * K + ss * 8;
    const __hip_bfloat16* gB = Bw + (size_t)(tileN + wid * 32 + lr) * K + ss * 8;

    floatx4 acc[4][4];
    #pragma unroll
    for (int i = 0; i < 4; ++i)
        #pragma unroll
        for (int j = 0; j < 4; ++j)
            acc[i][j] = (floatx4){0.f, 0.f, 0.f, 0.f};

#define STAGE2(b, k0)                                                                     \
    {                                                                                     \
        _Pragma("unroll")                                                                 \
        for (int q = 0; q < 2; ++q)                                                       \
            __builtin_amdgcn_global_load_lds(                                             \
                (const __attribute__((address_space(1))) void*)(gA + (size_t)(q * 8) * K + (k0)), \
                (__attribute__((address_space(3))) void*)(&As[b][(wid * 2 + q) * 512]),   \
                16, 0, 0);                                                                \
        _Pragma("unroll")                                                                 \
        for (int q = 0; q < 4; ++q)                                                       \
            __builtin_amdgcn_global_load_lds(                                             \
                (const __attribute__((address_space(1))) void*)(gB + (size_t)(q * 8) * K + (k0)), \
                (__attribute__((address_space(3))) void*)(&Bs[b][(wid * 4 + q) * 512]),   \
                16, 0, 0);                                                                \
    }

    const int NT = K >> 6;              // BK=64 tiles

    // prologue: tiles 0 and 1 in flight; wait tile 0 (6 newest = tile 1 stay out)
    STAGE2(0, 0)
    STAGE2(1, 64)
    asm volatile("s_waitcnt vmcnt(6)\ns_barrier" ::: "memory");

    const int lsw = (lm & 7);           // read-side XOR term (row&7 == lm&7 here)

    for (int t = 0; t < NT; ++t) {
        const int b = t & 1;
        const short* pa = As[b];
        const short* pb = Bs[b];

        #pragma unroll
        for (int ks = 0; ks < 2; ++ks) {
            short8 af[4], bfr[4];
            const int cs = ks * 4 + g;
            const int so = (cs ^ lsw) * 8;
            #pragma unroll
            for (int i = 0; i < 4; ++i)
                af[i] = *(const short8*)(pa + (wm + i * 16 + lm) * 64 + so);
            #pragma unroll
            for (int j = 0; j < 4; ++j)
                bfr[j] = *(const short8*)(pb + (wn + j * 16 + lm) * 64 + so);

            __builtin_amdgcn_s_setprio(1);
            #pragma unroll
            for (int i = 0; i < 4; ++i)
                #pragma unroll
                for (int j = 0; j < 4; ++j)
                    acc[i][j] = __builtin_amdgcn_mfma_f32_16x16x32_bf16(af[i], bfr[j], acc[i][j], 0, 0, 0);
            __builtin_amdgcn_s_setprio(0);
        }

        if (t + 1 < NT) {
            // free buffer b for overwrite: my LDS reads done, everyone arrived
            asm volatile("s_waitcnt lgkmcnt(0)\ns_barrier" ::: "memory");
            if (t + 2 < NT) {
                STAGE2(b, (t + 2) * 64)
                // wait tile t+1 landed (6 newest outstanding = tile t+2's)
                asm volatile("s_waitcnt vmcnt(6)\ns_barrier" ::: "memory");
            } else {
                asm volatile("s_waitcnt vmcnt(0)\ns_barrier" ::: "memory");
            }
        }
    }
#undef STAGE2

    // epilogue: C/D layout col = lane&15, row = (lane>>4)*4 + reg
    const int rbase = g * 4;
    #pragma unroll
    for (int i = 0; i < 4; ++i) {
        const int rl = wm + i * 16 + rbase;
        #pragma unroll
        for (int j = 0; j < 4; ++j) {
            const int n = tileN + wn + j * 16 + lm;
            const float bv = bias[n];
            #pragma unroll
            for (int r = 0; r < 4; ++r) {
                const int m = tileM + rl + r;
                const size_t idx = (size_t)m * N + n;
                float v = acc[i][j][r] + bv;
                if (EPI == 0) {
                    ((__hip_bfloat16*)out)[idx] = __float2bfloat16(v);
                } else if (EPI == 1) {
                    v += ((const float*)res)[idx];
                    ((float*)out)[idx] = v;
                } else if (EPI == 2) {
                    v = v > 0.f ? v : 0.f;
                    ((__hip_bfloat16*)out)[idx] = __float2bfloat16(v);
                } else {
                    v += __bfloat162float(((const __hip_bfloat16*)res)[idx]);
                    ((float*)out)[idx] = v;
                }
            }
        }
    }
}

// ---------------- windowed attention via MFMA, one wave per (window, head) -----
// Full-tensor version: blockIdx.x = batch*256 + window.
__global__ __launch_bounds__(64) void attn_kernel(
    const __hip_bfloat16* __restrict__ qkv,   // NTOK x 1536 bf16
    const float* __restrict__ pos,            // 15*15 fp32
    __hip_bfloat16* __restrict__ obuf)        // NTOK x 512 bf16
{
    __shared__ __align__(16) short vt[32][72];   // V^T: [dim][key], pitch 144 B
    __shared__ __align__(16) short pl[64][72];   // P:   [q][key] bf16, pitch 144 B
    __shared__ float ps[232];

    const int bwin = blockIdx.x;     // 0..1023
    const int win  = bwin & 255;     // window within image
    const int bat  = bwin >> 8;      // batch image 0..3
    const int h    = blockIdx.y;     // 0..15
    const int l    = threadIdx.x;    // 0..63
    const int l15  = l & 15;
    const int g    = l >> 4;         // 16-lane group 0..3
    const int g8   = g * 8;          // fragment k-offset (elements)

    const int base0 = bat * 16384 + (win >> 4) * 1024 + (win & 15) * 8; // window-origin token

    for (int u = l; u < 225; u += 64) ps[u] = pos[u];

    // ---- stage V^T: lane l owns token l's V row (32 dims) ----
    const int tok_l = base0 + (l >> 3) * 128 + (l & 7);
    const short8* vp = (const short8*)(qkv + (size_t)tok_l * N3E + 1024 + h * HD_);
    #pragma unroll
    for (int u = 0; u < 4; ++u) {
        short8 vv = vp[u];
        #pragma unroll
        for (int e = 0; e < 8; ++e) vt[u * 8 + e][l] = vv[e];
    }

    // ---- Q/K fragments: direct per-lane 16B loads (row-contiguous in qkv) ----
    const int tokbase = base0 + (l15 >> 3) * 128 + (l15 & 7);
    short8 qf[4], kf[4];
    #pragma unroll
    for (int j = 0; j < 4; ++j) {
        const size_t tb = (size_t)(tokbase + 256 * j) * N3E + h * HD_ + g8;
        qf[j] = *(const short8*)(qkv + tb);
        kf[j] = *(const short8*)(qkv + tb + 512);
    }
    __syncthreads();   // vt visible

    // ---- QK^T: st[i][j] = keys i*16.., queries j*16..  (D[key][q]) ----
    floatx4 st[4][4];
    #pragma unroll
    for (int i = 0; i < 4; ++i)
        #pragma unroll
        for (int j = 0; j < 4; ++j)
            st[i][j] = __builtin_amdgcn_mfma_f32_16x16x32_bf16(
                kf[i], qf[j], (floatx4){0.f, 0.f, 0.f, 0.f}, 0, 0, 0);

    // ---- softmax per query (col = l15 within q-tile j) ----
    const float scale = 0.17677669529663687f;   // 1/sqrt(32)
    int kb[4];
    #pragma unroll
    for (int r = 0; r < 4; ++r) {
        const int qq = g * 4 + r;
        kb[r] = (qq >> 3) * 15 + (qq & 7);      // key's bias contribution
    }

    #pragma unroll
    for (int j = 0; j < 4; ++j) {
        const int q   = j * 16 + l15;
        const int qoi = 112 - (q >> 3) * 15 - (q & 7);
        float p[16];
        float mx = -1e30f;
        #pragma unroll
        for (int i = 0; i < 4; ++i)
            #pragma unroll
            for (int r = 0; r < 4; ++r) {
                const float sv = st[i][j][r] * scale + ps[30 * i + kb[r] + qoi];
                p[i * 4 + r] = sv;
                mx = fmaxf(mx, sv);
            }
        mx = fmaxf(mx, __shfl_xor(mx, 16));
        mx = fmaxf(mx, __shfl_xor(mx, 32));
        float sum = 0.f;
        #pragma unroll
        for (int u = 0; u < 16; ++u) { p[u] = __expf(p[u] - mx); sum += p[u]; }
        sum += __shfl_xor(sum, 16);
        sum += __shfl_xor(sum, 32);
        const float inv = 1.f / sum;
        #pragma unroll
        for (int i = 0; i < 4; ++i) {
            short4t pk;
            #pragma unroll
            for (int r = 0; r < 4; ++r) pk[r] = f2bs(p[i * 4 + r] * inv);
            *(short4t*)&pl[q][i * 16 + g * 4] = pk;
        }
    }
    __syncthreads();   // pl visible

    // ---- PV: O[q][dim] += P[q][k] * V[k][dim], k in 2 steps of 32 ----
    short8 vb[2][2];   // [nt dim-tile][kk k-step]
    #pragma unroll
    for (int nt = 0; nt < 2; ++nt)
        #pragma unroll
        for (int kk = 0; kk < 2; ++kk)
            vb[nt][kk] = *(const short8*)&vt[nt * 16 + l15][kk * 32 + g8];

    floatx4 o[4][2];
    #pragma unroll
    for (int j = 0; j < 4; ++j)
        #pragma unroll
        for (int nt = 0; nt < 2; ++nt)
            o[j][nt] = (floatx4){0.f, 0.f, 0.f, 0.f};

    #pragma unroll
    for (int j = 0; j < 4; ++j) {
        #pragma unroll
        for (int kk = 0; kk < 2; ++kk) {
            const short8 pa = *(const short8*)&pl[j * 16 + l15][kk * 32 + g8];
            #pragma unroll
            for (int nt = 0; nt < 2; ++nt)
                o[j][nt] = __builtin_amdgcn_mfma_f32_16x16x32_bf16(
                    pa, vb[nt][kk], o[j][nt], 0, 0, 0);
        }
    }

    // ---- store O: D layout col=dim=nt*16+l15, row=q-in-tile=g*4+r ----
    #pragma unroll
    for (int r = 0; r < 4; ++r) {
        const int qq = g * 4 + r;
        const int tb = base0 + (qq >> 3) * 128 + (qq & 7);
        #pragma unroll
        for (int j = 0; j < 4; ++j) {
            __hip_bfloat16* op = obuf + (size_t)(tb + 256 * j) * E_ + h * HD_ + l15;
            op[0]  = __float2bfloat16(o[j][0][r]);
            op[16] = __float2bfloat16(o[j][1][r]);
        }
    }
}

// ---------------- LayerNorm over E=512, one wave per row ----------------
template<int OUTMODE>  // 0: bf16 out, 1: float out
__global__ __launch_bounds__(256) void ln_kernel(
    const float* __restrict__ in, const float* __restrict__ gw,
    const float* __restrict__ gb, void* __restrict__ out)
{
    const int row  = blockIdx.x * 4 + (threadIdx.x >> 6);
    const int lane = threadIdx.x & 63;
    const float* rp = in + (size_t)row * 512 + lane * 8;
    float4 v0 = *(const float4*)rp;
    float4 v1 = *(const float4*)(rp + 4);
    float s  = v0.x + v0.y + v0.z + v0.w + v1.x + v1.y + v1.z + v1.w;
    float sq = v0.x * v0.x + v0.y * v0.y + v0.z * v0.z + v0.w * v0.w
             + v1.x * v1.x + v1.y * v1.y + v1.z * v1.z + v1.w * v1.w;
    #pragma unroll
    for (int off = 32; off > 0; off >>= 1) {
        s  += __shfl_xor(s, off);
        sq += __shfl_xor(sq, off);
    }
    const float mean = s * (1.f / 512.f);
    const float var  = sq * (1.f / 512.f) - mean * mean;
    const float rstd = rsqrtf(var + 1e-5f);
    const int c = lane * 8;
    float4 g0 = *(const float4*)(gw + c), g1 = *(const float4*)(gw + c + 4);
    float4 b0 = *(const float4*)(gb + c), b1 = *(const float4*)(gb + c + 4);
    float r[8];
    r[0] = (v0.x - mean) * rstd * g0.x + b0.x;
    r[1] = (v0.y - mean) * rstd * g0.y + b0.y;
    r[2] = (v0.z - mean) * rstd * g0.z + b0.z;
    r[3] = (v0.w - mean) * rstd * g0.w + b0.w;
    r[4] = (v1.x - mean) * rstd * g1.x + b1.x;
    r[5] = (v1.y - mean) * rstd * g1.y + b1.y;
    r[6] = (v1.z - mean) * rstd * g1.z + b1.z;
    r[7] = (v1.w - mean) * rstd * g1.w + b1.w;
    if (OUTMODE == 0) {
        short8 o;
        #pragma unroll
        for (int e = 0; e < 8; ++e) o[e] = f2bs(r[e]);
        *(short8*)((__hip_bfloat16*)out + (size_t)row * 512 + c) = o;
    } else {
        float* po = (float*)out + (size_t)row * 512 + c;
        *(float4*)po       = make_float4(r[0], r[1], r[2], r[3]);
        *(float4*)(po + 4) = make_float4(r[4], r[5], r[6], r[7]);
    }
}

// ---------------- workspace layout (bytes) — high-water ~390 MiB ----------------
// (fill counter shows harness zeroes 512 MiB of d_ws each iter -> ws >= 512 MiB)
static const size_t OFF_WQKV = 0;                       // 1536*512*2    = 1,572,864
static const size_t OFF_WOUT = 1572864;                 // 512*512*2     =   524,288
static const size_t OFF_W1   = 2097152;                 // 2048*512*2    = 2,097,152
static const size_t OFF_W2   = 4194304;                 // 512*2048*2    = 2,097,152
static const size_t OFF_XB   = 6291456;                 // 65536*512*2   = 67,108,864
static const size_t OFF_ZB   = 73400320;                // 65536*512*2   = 67,108,864
static const size_t OFF_QKVC = 140509184;               // 65536*1536*2  = 201,326,592
static const size_t OFF_OBUFC= 341835776;               // 65536*512*2   = 67,108,864
static const size_t OFF_H1C  = OFF_QKVC;                // 65536*2048*2  = 268,435,456 (aliases qkv+obuf, both dead)
// end = 408,944,640 (~390 MiB). s1/s2 live in d_out (128 MB fp32), LN2 in-place.

extern "C" void kernel_launch(void* const* d_in, const int* in_sizes, int n_in,
                              void* d_out, int out_size, void* d_ws, size_t ws_size,
                              hipStream_t stream) {
    (void)in_sizes; (void)n_in; (void)out_size; (void)ws_size;
    const float* x    = (const float*)d_in[0];
    const float* wqkv = (const float*)d_in[1];
    const float* bqkv = (const float*)d_in[2];
    const float* wout = (const float*)d_in[3];
    const float* bout = (const float*)d_in[4];
    const float* pos  = (const float*)d_in[5];
    const float* w1   = (const float*)d_in[6];
    const float* b1   = (const float*)d_in[7];
    const float* w2   = (const float*)d_in[8];
    const float* b2   = (const float*)d_in[9];
    const float* g1   = (const float*)d_in[10];
    const float* bb1  = (const float*)d_in[11];
    const float* g2   = (const float*)d_in[12];
    const float* bb2  = (const float*)d_in[13];
    float* outp = (float*)d_out;

    char* ws = (char*)d_ws;
    __hip_bfloat16* wqkv_b = (__hip_bfloat16*)(ws + OFF_WQKV);
    __hip_bfloat16* wout_b = (__hip_bfloat16*)(ws + OFF_WOUT);
    __hip_bfloat16* w1_b   = (__hip_bfloat16*)(ws + OFF_W1);
    __hip_bfloat16* w2_b   = (__hip_bfloat16*)(ws + OFF_W2);
    __hip_bfloat16* xb     = (__hip_bfloat16*)(ws + OFF_XB);
    __hip_bfloat16* zb     = (__hip_bfloat16*)(ws + OFF_ZB);
    __hip_bfloat16* qkvc   = (__hip_bfloat16*)(ws + OFF_QKVC);
    __hip_bfloat16* obufc  = (__hip_bfloat16*)(ws + OFF_OBUFC);
    __hip_bfloat16* h1c    = (__hip_bfloat16*)(ws + OFF_H1C);

    // fp32 -> bf16 conversions
    {
        int n;
        n = N3E * E_;    cvt_kernel<<<(n / 8 + 255) / 256, 256, 0, stream>>>(wqkv, wqkv_b, n);
        n = E_ * E_;     cvt_kernel<<<(n / 8 + 255) / 256, 256, 0, stream>>>(wout, wout_b, n);
        n = DFF_ * E_;   cvt_kernel<<<(n / 8 + 255) / 256, 256, 0, stream>>>(w1, w1_b, n);
        n = E_ * DFF_;   cvt_kernel<<<(n / 8 + 255) / 256, 256, 0, stream>>>(w2, w2_b, n);
        n = NTOK * E_;   cvt_kernel<<<(n / 8 + 255) / 256, 256, 0, stream>>>(x, xb, n);
    }

    // 1. qkv = x @ Wqkv^T + b  (full tensor, 103 GFLOP)
    gemm2_kernel<0><<<dim3(N3E / 256, NTOK / 128), 512, 0, stream>>>(
        xb, wqkv_b, bqkv, nullptr, qkvc, NTOK, N3E, E_);
    // 2. windowed attention over all 4 images
    attn_kernel<<<dim3(1024, NH_), 64, 0, stream>>>(qkvc, pos, obufc);
    // 3. s1 = attn @ Wout^T + bout + x  (fp32 into d_out)
    gemm2_kernel<1><<<dim3(E_ / 256, NTOK / 128), 512, 0, stream>>>(
        obufc, wout_b, bout, x, outp, NTOK, E_, E_);

    // 4. z = LN1(s1)  (s1 lives in d_out; z -> zb bf16)
    ln_kernel<0><<<NTOK / 4, 256, 0, stream>>>(outp, g1, bb1, zb);

    // 5. h1 = relu(z @ W1^T + b1)   6. s2 = h1 @ W2^T + b2 + z -> d_out
    gemm2_kernel<2><<<dim3(DFF_ / 256, NTOK / 128), 512, 0, stream>>>(
        zb, w1_b, b1, nullptr, h1c, NTOK, DFF_, E_);
    gemm2_kernel<3><<<dim3(E_ / 256, NTOK / 128), 512, 0, stream>>>(
        h1c, w2_b, b2, zb, outp, NTOK, E_, DFF_);

    // 7. out = LN2(s2) in-place on d_out
    ln_kernel<1><<<NTOK / 4, 256, 0, stream>>>(outp, g2, bb2, outp);
}

// Round 5
// 1073.953 us; speedup vs baseline: 1.1012x; 1.1012x over previous
//
#include <hip/hip_runtime.h>
#include <hip/hip_bf16.h>

// ---------------- problem constants ----------------
#define NTOK   65536          // B*H*W = 4*128*128
#define E_     512
#define NH_    16
#define HD_    32
#define DFF_   2048
#define N3E    1536           // 3*E

typedef __attribute__((ext_vector_type(8))) short short8;
typedef __attribute__((ext_vector_type(4))) short short4t;
typedef __attribute__((ext_vector_type(4))) float floatx4;

__device__ inline float b2f(short u) {
    union { float f; unsigned int i; } x;
    x.i = ((unsigned int)(unsigned short)u) << 16;
    return x.f;
}
__device__ inline short f2bs(float f) {
    __hip_bfloat16 h = __float2bfloat16(f);
    return *reinterpret_cast<short*>(&h);
}

// ---------------- fp32 -> bf16 convert ----------------
__global__ __launch_bounds__(256) void cvt_kernel(const float* __restrict__ in,
                                                  __hip_bfloat16* __restrict__ out, int n) {
    int i = (blockIdx.x * 256 + threadIdx.x) * 8;
    if (i >= n) return;
    if (i + 7 < n) {
        float4 a = *(const float4*)(in + i);
        float4 b = *(const float4*)(in + i + 4);
        short8 o;
        o[0] = f2bs(a.x); o[1] = f2bs(a.y); o[2] = f2bs(a.z); o[3] = f2bs(a.w);
        o[4] = f2bs(b.x); o[5] = f2bs(b.y); o[6] = f2bs(b.z); o[7] = f2bs(b.w);
        *(short8*)(out + i) = o;
    } else {
        for (int u = i; u < n; ++u) out[u] = __float2bfloat16(in[u]);
    }
}

// ---------------- pipelined MFMA GEMM v3: C = A @ Bw^T + bias (+epilogue) -----
// BM=128, BN=128, BK=32, 256 threads = 4 waves (2x2), 64x64 C per wave.
// Double-buffered LDS = 32 KB -> up to 4 blocks/CU (TLP fills barrier stalls;
// R4's 96 KB/1-block variant measured Occupancy 22.7%, MfmaUtil 20.5%).
// Counted vmcnt(4): next tile's 4 loads stay in flight across barriers.
// LDS 4-slot XOR swizzle: physical slot = logical ^ (row&3); applied as
// pre-swizzled GLOBAL source + swizzled ds_read (both-sides involution).
// EPI 0: store bf16(out)                      (qkv proj)
// EPI 1: + res(float) -> store float          (out proj + x residual)
// EPI 2: relu -> store bf16                   (lin1)
// EPI 3: + res(bf16)  -> store float          (lin2 + z residual)
template<int EPI>
__global__ __launch_bounds__(256, 4) void gemm3_kernel(
    const __hip_bfloat16* __restrict__ A,
    const __hip_bfloat16* __restrict__ Bw,
    const float* __restrict__ bias,
    const void* __restrict__ res,
    void* __restrict__ out,
    int M, int N, int K)
{
    __shared__ __align__(16) short As[2][128 * 32];   // 8 KB x 2
    __shared__ __align__(16) short Bs[2][128 * 32];   // 8 KB x 2

    const int tid  = threadIdx.x;
    const int wid  = tid >> 6;          // 0..3
    const int lane = tid & 63;
    const int tileN = blockIdx.x * 128;
    const int tileM = blockIdx.y * 128;

    const int wm = (wid >> 1) * 64;     // wave quadrant inside 128x128
    const int wn = (wid & 1) * 64;
    const int lm = lane & 15;
    const int g  = lane >> 4;

    // staging: each global_load_lds covers 16 rows x 32 cols (1024 B linear).
    // lane l -> row l>>2, physical 16B-slot l&3. Physical slot s at row r
    // holds logical slot s^(r&3) -> source logical slot = (l&3)^(lr&3).
    const int lr = lane >> 2;           // row within 16-row chunk
    const int sl = (lane & 3) ^ (lr & 3);

    const __hip_bfloat16* gA = A  + (size_t)(tileM + wid * 32 + lr) * K + sl * 8;
    const __hip_bfloat16* gB = Bw + (size_t)(tileN + wid * 32 + lr) * K + sl * 8;

    floatx4 acc[4][4];
    #pragma unroll
    for (int i = 0; i < 4; ++i)
        #pragma unroll
        for (int j = 0; j < 4; ++j)
            acc[i][j] = (floatx4){0.f, 0.f, 0.f, 0.f};

#define STAGE3(b, k0)                                                                     \
    {                                                                                     \
        _Pragma("unroll")                                                                 \
        for (int q = 0; q < 2; ++q)                                                       \
            __builtin_amdgcn_global_load_lds(                                             \
                (const __attribute__((address_space(1))) void*)(gA + (size_t)(q * 16) * K + (k0)), \
                (__attribute__((address_space(3))) void*)(&As[b][(wid * 2 + q) * 512]),   \
                16, 0, 0);                                                                \
        _Pragma("unroll")                                                                 \
        for (int q = 0; q < 2; ++q)                                                       \
            __builtin_amdgcn_global_load_lds(                                             \
                (const __attribute__((address_space(1))) void*)(gB + (size_t)(q * 16) * K + (k0)), \
                (__attribute__((address_space(3))) void*)(&Bs[b][(wid * 2 + q) * 512]),   \
                16, 0, 0);                                                                \
    }

    const int NT = K >> 5;              // BK=32 tiles

    // prologue: tiles 0,1 in flight (8 instr/wave); wait tile 0 -> vmcnt(4)
    STAGE3(0, 0)
    STAGE3(1, 32)
    asm volatile("s_waitcnt vmcnt(4)\ns_barrier" ::: "memory");

    const int so = (g ^ (lm & 3)) * 8;  // swizzled read slot (row&3 == lm&3)

    for (int t = 0; t < NT; ++t) {
        const int b = t & 1;
        const short* pa = As[b];
        const short* pb = Bs[b];

        short8 af[4], bfr[4];
        #pragma unroll
        for (int i = 0; i < 4; ++i)
            af[i] = *(const short8*)(pa + (wm + i * 16 + lm) * 32 + so);
        #pragma unroll
        for (int j = 0; j < 4; ++j)
            bfr[j] = *(const short8*)(pb + (wn + j * 16 + lm) * 32 + so);

        __builtin_amdgcn_s_setprio(1);
        #pragma unroll
        for (int i = 0; i < 4; ++i)
            #pragma unroll
            for (int j = 0; j < 4; ++j)
                acc[i][j] = __builtin_amdgcn_mfma_f32_16x16x32_bf16(af[i], bfr[j], acc[i][j], 0, 0, 0);
        __builtin_amdgcn_s_setprio(0);

        if (t + 1 < NT) {
            // free buffer b: my LDS reads done, all waves arrived
            asm volatile("s_waitcnt lgkmcnt(0)\ns_barrier" ::: "memory");
            if (t + 2 < NT) {
                STAGE3(b, (t + 2) * 32)
                // tile t+1 landed (4 newest outstanding = tile t+2's)
                asm volatile("s_waitcnt vmcnt(4)\ns_barrier" ::: "memory");
            } else {
                asm volatile("s_waitcnt vmcnt(0)\ns_barrier" ::: "memory");
            }
        }
    }
#undef STAGE3

    // epilogue: C/D layout col = lane&15, row = (lane>>4)*4 + reg
    const int rbase = g * 4;
    #pragma unroll
    for (int i = 0; i < 4; ++i) {
        const int rl = wm + i * 16 + rbase;
        #pragma unroll
        for (int j = 0; j < 4; ++j) {
            const int n = tileN + wn + j * 16 + lm;
            const float bv = bias[n];
            #pragma unroll
            for (int r = 0; r < 4; ++r) {
                const int m = tileM + rl + r;
                const size_t idx = (size_t)m * N + n;
                float v = acc[i][j][r] + bv;
                if (EPI == 0) {
                    ((__hip_bfloat16*)out)[idx] = __float2bfloat16(v);
                } else if (EPI == 1) {
                    v += ((const float*)res)[idx];
                    ((float*)out)[idx] = v;
                } else if (EPI == 2) {
                    v = v > 0.f ? v : 0.f;
                    ((__hip_bfloat16*)out)[idx] = __float2bfloat16(v);
                } else {
                    v += __bfloat162float(((const __hip_bfloat16*)res)[idx]);
                    ((float*)out)[idx] = v;
                }
            }
        }
    }
}

// ---------------- windowed attention via MFMA, one wave per (window, head) -----
// Full-tensor version: blockIdx.x = batch*256 + window.
__global__ __launch_bounds__(64) void attn_kernel(
    const __hip_bfloat16* __restrict__ qkv,   // NTOK x 1536 bf16
    const float* __restrict__ pos,            // 15*15 fp32
    __hip_bfloat16* __restrict__ obuf)        // NTOK x 512 bf16
{
    __shared__ __align__(16) short vt[32][72];   // V^T: [dim][key], pitch 144 B
    __shared__ __align__(16) short pl[64][72];   // P:   [q][key] bf16, pitch 144 B
    __shared__ float ps[232];

    const int bwin = blockIdx.x;     // 0..1023
    const int win  = bwin & 255;     // window within image
    const int bat  = bwin >> 8;      // batch image 0..3
    const int h    = blockIdx.y;     // 0..15
    const int l    = threadIdx.x;    // 0..63
    const int l15  = l & 15;
    const int g    = l >> 4;         // 16-lane group 0..3
    const int g8   = g * 8;          // fragment k-offset (elements)

    const int base0 = bat * 16384 + (win >> 4) * 1024 + (win & 15) * 8; // window-origin token

    for (int u = l; u < 225; u += 64) ps[u] = pos[u];

    // ---- stage V^T: lane l owns token l's V row (32 dims) ----
    const int tok_l = base0 + (l >> 3) * 128 + (l & 7);
    const short8* vp = (const short8*)(qkv + (size_t)tok_l * N3E + 1024 + h * HD_);
    #pragma unroll
    for (int u = 0; u < 4; ++u) {
        short8 vv = vp[u];
        #pragma unroll
        for (int e = 0; e < 8; ++e) vt[u * 8 + e][l] = vv[e];
    }

    // ---- Q/K fragments: direct per-lane 16B loads (row-contiguous in qkv) ----
    const int tokbase = base0 + (l15 >> 3) * 128 + (l15 & 7);
    short8 qf[4], kf[4];
    #pragma unroll
    for (int j = 0; j < 4; ++j) {
        const size_t tb = (size_t)(tokbase + 256 * j) * N3E + h * HD_ + g8;
        qf[j] = *(const short8*)(qkv + tb);
        kf[j] = *(const short8*)(qkv + tb + 512);
    }
    __syncthreads();   // vt visible

    // ---- QK^T: st[i][j] = keys i*16.., queries j*16..  (D[key][q]) ----
    floatx4 st[4][4];
    #pragma unroll
    for (int i = 0; i < 4; ++i)
        #pragma unroll
        for (int j = 0; j < 4; ++j)
            st[i][j] = __builtin_amdgcn_mfma_f32_16x16x32_bf16(
                kf[i], qf[j], (floatx4){0.f, 0.f, 0.f, 0.f}, 0, 0, 0);

    // ---- softmax per query (col = l15 within q-tile j) ----
    const float scale = 0.17677669529663687f;   // 1/sqrt(32)
    int kb[4];
    #pragma unroll
    for (int r = 0; r < 4; ++r) {
        const int qq = g * 4 + r;
        kb[r] = (qq >> 3) * 15 + (qq & 7);      // key's bias contribution
    }

    #pragma unroll
    for (int j = 0; j < 4; ++j) {
        const int q   = j * 16 + l15;
        const int qoi = 112 - (q >> 3) * 15 - (q & 7);
        float p[16];
        float mx = -1e30f;
        #pragma unroll
        for (int i = 0; i < 4; ++i)
            #pragma unroll
            for (int r = 0; r < 4; ++r) {
                const float sv = st[i][j][r] * scale + ps[30 * i + kb[r] + qoi];
                p[i * 4 + r] = sv;
                mx = fmaxf(mx, sv);
            }
        mx = fmaxf(mx, __shfl_xor(mx, 16));
        mx = fmaxf(mx, __shfl_xor(mx, 32));
        float sum = 0.f;
        #pragma unroll
        for (int u = 0; u < 16; ++u) { p[u] = __expf(p[u] - mx); sum += p[u]; }
        sum += __shfl_xor(sum, 16);
        sum += __shfl_xor(sum, 32);
        const float inv = 1.f / sum;
        #pragma unroll
        for (int i = 0; i < 4; ++i) {
            short4t pk;
            #pragma unroll
            for (int r = 0; r < 4; ++r) pk[r] = f2bs(p[i * 4 + r] * inv);
            *(short4t*)&pl[q][i * 16 + g * 4] = pk;
        }
    }
    __syncthreads();   // pl visible

    // ---- PV: O[q][dim] += P[q][k] * V[k][dim], k in 2 steps of 32 ----
    short8 vb[2][2];   // [nt dim-tile][kk k-step]
    #pragma unroll
    for (int nt = 0; nt < 2; ++nt)
        #pragma unroll
        for (int kk = 0; kk < 2; ++kk)
            vb[nt][kk] = *(const short8*)&vt[nt * 16 + l15][kk * 32 + g8];

    floatx4 o[4][2];
    #pragma unroll
    for (int j = 0; j < 4; ++j)
        #pragma unroll
        for (int nt = 0; nt < 2; ++nt)
            o[j][nt] = (floatx4){0.f, 0.f, 0.f, 0.f};

    #pragma unroll
    for (int j = 0; j < 4; ++j) {
        #pragma unroll
        for (int kk = 0; kk < 2; ++kk) {
            const short8 pa = *(const short8*)&pl[j * 16 + l15][kk * 32 + g8];
            #pragma unroll
            for (int nt = 0; nt < 2; ++nt)
                o[j][nt] = __builtin_amdgcn_mfma_f32_16x16x32_bf16(
                    pa, vb[nt][kk], o[j][nt], 0, 0, 0);
        }
    }

    // ---- store O: D layout col=dim=nt*16+l15, row=q-in-tile=g*4+r ----
    #pragma unroll
    for (int r = 0; r < 4; ++r) {
        const int qq = g * 4 + r;
        const int tb = base0 + (qq >> 3) * 128 + (qq & 7);
        #pragma unroll
        for (int j = 0; j < 4; ++j) {
            __hip_bfloat16* op = obuf + (size_t)(tb + 256 * j) * E_ + h * HD_ + l15;
            op[0]  = __float2bfloat16(o[j][0][r]);
            op[16] = __float2bfloat16(o[j][1][r]);
        }
    }
}

// ---------------- LayerNorm over E=512, one wave per row ----------------
template<int OUTMODE>  // 0: bf16 out, 1: float out
__global__ __launch_bounds__(256) void ln_kernel(
    const float* __restrict__ in, const float* __restrict__ gw,
    const float* __restrict__ gb, void* __restrict__ out)
{
    const int row  = blockIdx.x * 4 + (threadIdx.x >> 6);
    const int lane = threadIdx.x & 63;
    const float* rp = in + (size_t)row * 512 + lane * 8;
    float4 v0 = *(const float4*)rp;
    float4 v1 = *(const float4*)(rp + 4);
    float s  = v0.x + v0.y + v0.z + v0.w + v1.x + v1.y + v1.z + v1.w;
    float sq = v0.x * v0.x + v0.y * v0.y + v0.z * v0.z + v0.w * v0.w
             + v1.x * v1.x + v1.y * v1.y + v1.z * v1.z + v1.w * v1.w;
    #pragma unroll
    for (int off = 32; off > 0; off >>= 1) {
        s  += __shfl_xor(s, off);
        sq += __shfl_xor(sq, off);
    }
    const float mean = s * (1.f / 512.f);
    const float var  = sq * (1.f / 512.f) - mean * mean;
    const float rstd = rsqrtf(var + 1e-5f);
    const int c = lane * 8;
    float4 g0 = *(const float4*)(gw + c), g1 = *(const float4*)(gw + c + 4);
    float4 b0 = *(const float4*)(gb + c), b1 = *(const float4*)(gb + c + 4);
    float r[8];
    r[0] = (v0.x - mean) * rstd * g0.x + b0.x;
    r[1] = (v0.y - mean) * rstd * g0.y + b0.y;
    r[2] = (v0.z - mean) * rstd * g0.z + b0.z;
    r[3] = (v0.w - mean) * rstd * g0.w + b0.w;
    r[4] = (v1.x - mean) * rstd * g1.x + b1.x;
    r[5] = (v1.y - mean) * rstd * g1.y + b1.y;
    r[6] = (v1.z - mean) * rstd * g1.z + b1.z;
    r[7] = (v1.w - mean) * rstd * g1.w + b1.w;
    if (OUTMODE == 0) {
        short8 o;
        #pragma unroll
        for (int e = 0; e < 8; ++e) o[e] = f2bs(r[e]);
        *(short8*)((__hip_bfloat16*)out + (size_t)row * 512 + c) = o;
    } else {
        float* po = (float*)out + (size_t)row * 512 + c;
        *(float4*)po       = make_float4(r[0], r[1], r[2], r[3]);
        *(float4*)(po + 4) = make_float4(r[4], r[5], r[6], r[7]);
    }
}

// ---------------- workspace layout (bytes) — high-water ~390 MiB ----------------
static const size_t OFF_WQKV = 0;                       // 1536*512*2    = 1,572,864
static const size_t OFF_WOUT = 1572864;                 // 512*512*2     =   524,288
static const size_t OFF_W1   = 2097152;                 // 2048*512*2    = 2,097,152
static const size_t OFF_W2   = 4194304;                 // 512*2048*2    = 2,097,152
static const size_t OFF_XB   = 6291456;                 // 65536*512*2   = 67,108,864
static const size_t OFF_ZB   = 73400320;                // 65536*512*2   = 67,108,864
static const size_t OFF_QKVC = 140509184;               // 65536*1536*2  = 201,326,592
static const size_t OFF_OBUFC= 341835776;               // 65536*512*2   = 67,108,864
static const size_t OFF_H1C  = OFF_QKVC;                // 65536*2048*2  = 268,435,456 (aliases qkv+obuf, both dead)
// end = 408,944,640 (~390 MiB). s1/s2 live in d_out (128 MB fp32), LN2 in-place.

extern "C" void kernel_launch(void* const* d_in, const int* in_sizes, int n_in,
                              void* d_out, int out_size, void* d_ws, size_t ws_size,
                              hipStream_t stream) {
    (void)in_sizes; (void)n_in; (void)out_size; (void)ws_size;
    const float* x    = (const float*)d_in[0];
    const float* wqkv = (const float*)d_in[1];
    const float* bqkv = (const float*)d_in[2];
    const float* wout = (const float*)d_in[3];
    const float* bout = (const float*)d_in[4];
    const float* pos  = (const float*)d_in[5];
    const float* w1   = (const float*)d_in[6];
    const float* b1   = (const float*)d_in[7];
    const float* w2   = (const float*)d_in[8];
    const float* b2   = (const float*)d_in[9];
    const float* g1   = (const float*)d_in[10];
    const float* bb1  = (const float*)d_in[11];
    const float* g2   = (const float*)d_in[12];
    const float* bb2  = (const float*)d_in[13];
    float* outp = (float*)d_out;

    char* ws = (char*)d_ws;
    __hip_bfloat16* wqkv_b = (__hip_bfloat16*)(ws + OFF_WQKV);
    __hip_bfloat16* wout_b = (__hip_bfloat16*)(ws + OFF_WOUT);
    __hip_bfloat16* w1_b   = (__hip_bfloat16*)(ws + OFF_W1);
    __hip_bfloat16* w2_b   = (__hip_bfloat16*)(ws + OFF_W2);
    __hip_bfloat16* xb     = (__hip_bfloat16*)(ws + OFF_XB);
    __hip_bfloat16* zb     = (__hip_bfloat16*)(ws + OFF_ZB);
    __hip_bfloat16* qkvc   = (__hip_bfloat16*)(ws + OFF_QKVC);
    __hip_bfloat16* obufc  = (__hip_bfloat16*)(ws + OFF_OBUFC);
    __hip_bfloat16* h1c    = (__hip_bfloat16*)(ws + OFF_H1C);

    // fp32 -> bf16 conversions
    {
        int n;
        n = N3E * E_;    cvt_kernel<<<(n / 8 + 255) / 256, 256, 0, stream>>>(wqkv, wqkv_b, n);
        n = E_ * E_;     cvt_kernel<<<(n / 8 + 255) / 256, 256, 0, stream>>>(wout, wout_b, n);
        n = DFF_ * E_;   cvt_kernel<<<(n / 8 + 255) / 256, 256, 0, stream>>>(w1, w1_b, n);
        n = E_ * DFF_;   cvt_kernel<<<(n / 8 + 255) / 256, 256, 0, stream>>>(w2, w2_b, n);
        n = NTOK * E_;   cvt_kernel<<<(n / 8 + 255) / 256, 256, 0, stream>>>(x, xb, n);
    }

    // 1. qkv = x @ Wqkv^T + b  (full tensor, 103 GFLOP)
    gemm3_kernel<0><<<dim3(N3E / 128, NTOK / 128), 256, 0, stream>>>(
        xb, wqkv_b, bqkv, nullptr, qkvc, NTOK, N3E, E_);
    // 2. windowed attention over all 4 images
    attn_kernel<<<dim3(1024, NH_), 64, 0, stream>>>(qkvc, pos, obufc);
    // 3. s1 = attn @ Wout^T + bout + x  (fp32 into d_out)
    gemm3_kernel<1><<<dim3(E_ / 128, NTOK / 128), 256, 0, stream>>>(
        obufc, wout_b, bout, x, outp, NTOK, E_, E_);

    // 4. z = LN1(s1)  (s1 lives in d_out; z -> zb bf16)
    ln_kernel<0><<<NTOK / 4, 256, 0, stream>>>(outp, g1, bb1, zb);

    // 5. h1 = relu(z @ W1^T + b1)   6. s2 = h1 @ W2^T + b2 + z -> d_out
    gemm3_kernel<2><<<dim3(DFF_ / 128, NTOK / 128), 256, 0, stream>>>(
        zb, w1_b, b1, nullptr, h1c, NTOK, DFF_, E_);
    gemm3_kernel<3><<<dim3(E_ / 128, NTOK / 128), 256, 0, stream>>>(
        h1c, w2_b, b2, zb, outp, NTOK, E_, DFF_);

    // 7. out = LN2(s2) in-place on d_out
    ln_kernel<1><<<NTOK / 4, 256, 0, stream>>>(outp, g2, bb2, outp);
}